// Round 11
// baseline (359.924 us; speedup 1.0000x reference)
//
#include <hip/hip_runtime.h>

#define N_NODES 50000
#define N_PAD 50048      // rows padded: 782 buckets * 64 nodes exactly
#define N_EDGES 800000
#define HID 128
#define NBUCK 782        // = N_PAD / 64
#define BUCK_CAP 2048    // mean 1023, sigma ~32 -> +32 sigma headroom
#define ESC_CHUNK 2048
#define ESC_NCHUNK ((N_EDGES + ESC_CHUNK - 1) / ESC_CHUNK)   // 391

typedef unsigned int uint;
typedef __attribute__((ext_vector_type(8))) short short8;   // 8 bf16 = 4 VGPRs
typedef __attribute__((ext_vector_type(4))) float f32x4;
typedef __attribute__((ext_vector_type(2))) uint uint2e;
typedef __attribute__((ext_vector_type(4))) uint uint4e;

// ---- bf16 pack/unpack (RNE) ----
__device__ inline uint f2bf_pair(float x, float y) {
    uint ux = __float_as_uint(x);
    uint uy = __float_as_uint(y);
    ux = (ux + 0x7FFFu + ((ux >> 16) & 1u)) >> 16;
    uy = (uy + 0x7FFFu + ((uy >> 16) & 1u)) >> 16;
    return ux | (uy << 16);
}
__device__ inline float bf_lo(uint v) { return __uint_as_float(v << 16); }
__device__ inline float bf_hi(uint v) { return __uint_as_float(v & 0xFFFF0000u); }

// ---------------- strided-bucket CSR build ----------------
// Phase 1: append edges into fixed-stride bucket regions (bucket = dst>>6).
// XCD-local writes (class = bucket&7 handled by blocks with blockIdx&7==class),
// and NON-TEMPORAL edge reads so the 51MB dst/src stream does not flush the
// 50KB frontier working set out of L2 (that eviction was the 28MB write amp).
__global__ __launch_bounds__(256) void edge_scatter_kernel(const int* __restrict__ src,
                                                           const int* __restrict__ dst,
                                                           int* __restrict__ cursor16,
                                                           uint* __restrict__ col_tmp) {
    int cls = blockIdx.x & 7;
    int base = (blockIdx.x >> 3) * ESC_CHUNK;
#pragma unroll
    for (int i = 0; i < ESC_CHUNK / 256; ++i) {
        int e = base + i * 256 + threadIdx.x;
        if (e < N_EDGES) {
            int d = __builtin_nontemporal_load(&dst[e]);
            int s = __builtin_nontemporal_load(&src[e]);
            int b = d >> 6;
            uint val = (uint)s | ((uint)(d & 63) << 16);
            if ((b & 7) == cls) {
                int p = atomicAdd(&cursor16[b * 16], 1);
                if (p < BUCK_CAP)        // statistically impossible; guards OOB
                    col_tmp[(size_t)b * BUCK_CAP + p] = val;
            }
        }
    }
}

// Phase 2: per bucket, sort edges by local node in LDS, write back dense,
// emit per-node row_start/counts. In-place safe (full LDS copy before writes).
__global__ __launch_bounds__(256) void bucket_build_kernel(const int* __restrict__ cursor16,
                                                           uint* __restrict__ col_tmp,
                                                           int* __restrict__ row_start,
                                                           int* __restrict__ counts) {
    __shared__ uint edges[BUCK_CAP];
    __shared__ int cnt64[64], pre64[64], cur64[64];
    int b = blockIdx.x, t = threadIdx.x;
    int cnt = cursor16[b * 16];
    if (cnt > BUCK_CAP) cnt = BUCK_CAP;
    uint* region = col_tmp + (size_t)b * BUCK_CAP;
    for (int i = t; i < cnt; i += 256) edges[i] = __builtin_nontemporal_load(&region[i]);
    if (t < 64) { cnt64[t] = 0; cur64[t] = 0; }
    __syncthreads();
    for (int i = t; i < cnt; i += 256) atomicAdd(&cnt64[edges[i] >> 16], 1);
    __syncthreads();
    if (t == 0) {
        int s = 0;
        for (int j = 0; j < 64; ++j) { pre64[j] = s; s += cnt64[j]; }
    }
    __syncthreads();
    for (int i = t; i < cnt; i += 256) {
        uint e = edges[i];
        int dl = e >> 16;
        int p = atomicAdd(&cur64[dl], 1);
        region[pre64[dl] + p] = e & 0xFFFFu;
    }
    if (t < 64) {
        int node = b * 64 + t;
        row_start[node] = b * BUCK_CAP + pre64[t];
        counts[node] = cnt64[t];
    }
}

// ---------------- weights fp32 -> bf16 (once per launch) ----------------
__global__ void wconv_kernel(const float* __restrict__ W1, const float* __restrict__ W2,
                             const float* __restrict__ Wc,
                             uint* __restrict__ w1b, uint* __restrict__ w2b,
                             uint* __restrict__ wcb) {
    int i = blockIdx.x * 256 + threadIdx.x;   // bf16-pair index
    if (i < 3 * 128 * 64) {
        w1b[i] = f2bf_pair(W1[2 * i], W1[2 * i + 1]);
        w2b[i] = f2bf_pair(W2[2 * i], W2[2 * i + 1]);
    }
    if (i < 48 * 64) {   // Wc padded to 48 rows, rows 40-47 zero
        int r = i >> 6, q = i & 63;
        wcb[i] = (r < 40) ? f2bf_pair(Wc[r * 128 + 2 * q], Wc[r * 128 + 2 * q + 1]) : 0u;
    }
}

// ---------------- embedding -> bf16 h ----------------
__global__ void embed_kernel(const int* __restrict__ feats, const float* __restrict__ key_emb,
                             const float* __restrict__ val_emb, uint* __restrict__ h) {
    int idx = blockIdx.x * 256 + threadIdx.x;
    if (idx >= N_NODES * 32) return;
    int n = idx >> 5, q = idx & 31;
    int f0 = feats[2 * n], f1 = feats[2 * n + 1];
    float4 a = ((const float4*)key_emb)[f0 * 32 + q];
    float4 b = ((const float4*)val_emb)[f1 * 32 + q];
    float r0 = fmaxf(a.x + b.x, 0.f), r1 = fmaxf(a.y + b.y, 0.f);
    float r2 = fmaxf(a.z + b.z, 0.f), r3 = fmaxf(a.w + b.w, 0.f);
    uint2 o;
    o.x = f2bf_pair(r0, r1);
    o.y = f2bf_pair(r2, r3);
    *(uint2*)&h[(size_t)n * 64 + q * 2] = o;
}

// ---------------- GIN aggregation: z = h + sum_{u in N(n)} h[u] ----------------
// one wave per node; lane = uint2 (4 bf16 feats), 32 lanes/row; two wave halves
// gather two different neighbors per instruction; shfl_xor(32) combine.
// col reads + z stores non-temporal: keep L2 space for the h-row gathers.
__global__ __launch_bounds__(256) void agg_kernel(const uint* __restrict__ hb,
                                                  uint* __restrict__ zb,
                                                  const int* __restrict__ row_start,
                                                  const int* __restrict__ counts,
                                                  const uint* __restrict__ col) {
    int node = blockIdx.x * 4 + (threadIdx.x >> 6);
    int l = threadIdx.x & 63;
    int half = l >> 5, fl = l & 31;
    const uint2* hp2 = (const uint2*)hb;
    int s = __builtin_amdgcn_readfirstlane(row_start[node]);
    int c = __builtin_amdgcn_readfirstlane(counts[node]);
    float a0 = 0.f, a1 = 0.f, a2 = 0.f, a3 = 0.f;
    int j = 0;
    for (; j + 8 <= c; j += 8) {
        int u0 = (int)__builtin_nontemporal_load(&col[s + j + half]);
        int u1 = (int)__builtin_nontemporal_load(&col[s + j + 2 + half]);
        int u2 = (int)__builtin_nontemporal_load(&col[s + j + 4 + half]);
        int u3 = (int)__builtin_nontemporal_load(&col[s + j + 6 + half]);
        uint2 v0 = hp2[(size_t)u0 * 32 + fl];
        uint2 v1 = hp2[(size_t)u1 * 32 + fl];
        uint2 v2 = hp2[(size_t)u2 * 32 + fl];
        uint2 v3 = hp2[(size_t)u3 * 32 + fl];
        a0 += (bf_lo(v0.x) + bf_lo(v1.x)) + (bf_lo(v2.x) + bf_lo(v3.x));
        a1 += (bf_hi(v0.x) + bf_hi(v1.x)) + (bf_hi(v2.x) + bf_hi(v3.x));
        a2 += (bf_lo(v0.y) + bf_lo(v1.y)) + (bf_lo(v2.y) + bf_lo(v3.y));
        a3 += (bf_hi(v0.y) + bf_hi(v1.y)) + (bf_hi(v2.y) + bf_hi(v3.y));
    }
    for (; j + 2 <= c; j += 2) {
        int u = (int)__builtin_nontemporal_load(&col[s + j + half]);
        uint2 v = hp2[(size_t)u * 32 + fl];
        a0 += bf_lo(v.x); a1 += bf_hi(v.x); a2 += bf_lo(v.y); a3 += bf_hi(v.y);
    }
    if (j < c && half == 0) {
        int u = (int)__builtin_nontemporal_load(&col[s + j]);
        uint2 v = hp2[(size_t)u * 32 + fl];
        a0 += bf_lo(v.x); a1 += bf_hi(v.x); a2 += bf_lo(v.y); a3 += bf_hi(v.y);
    }
    a0 += __shfl_xor(a0, 32);
    a1 += __shfl_xor(a1, 32);
    a2 += __shfl_xor(a2, 32);
    a3 += __shfl_xor(a3, 32);
    if (half == 0) {
        uint2 hv = hp2[(size_t)node * 32 + fl];   // self term
        a0 += bf_lo(hv.x); a1 += bf_hi(hv.x); a2 += bf_lo(hv.y); a3 += bf_hi(hv.y);
        uint2e o;
        o.x = f2bf_pair(a0, a1);
        o.y = f2bf_pair(a2, a3);
        __builtin_nontemporal_store(o, (uint2e*)&zb[(size_t)node * 64 + fl * 2]);
    }
}

// ---------------- MFMA 2-layer MLP (+ fused classifier when LAST) ----------------
// 4 waves/block; wave w owns rows [blk*64 + w*16, +16), all 128 cols.
// mfma_f32_16x16x32_bf16: A lane l holds z[row][ks*32+(l>>4)*8 ..+8] with row=+(l&15);
// B identical addressing on row-major W (out = z@W^T); C/D col=l&15, row=(l>>4)*4+q.
template <bool LAST>
__global__ __launch_bounds__(256) void mlp_kernel(
    const uint* __restrict__ zb, uint* __restrict__ hout,
    const uint* __restrict__ w1b, const float* __restrict__ b1,
    const uint* __restrict__ w2b, const float* __restrict__ b2,
    const uint* __restrict__ wcb, float* __restrict__ out) {
    __shared__ float z1[64][132];   // stride 132 -> conflict-free, 33 KB
    int t = threadIdx.x;
    int w = t >> 6, l = t & 63;
    int lm = l & 15, lk = l >> 4;
    int row0 = blockIdx.x * 64;

    f32x4 acc[8];
    // ---- phase 1: z1 = relu(z @ W1^T + b1) ----
#pragma unroll
    for (int n = 0; n < 8; ++n) {
        float bv = b1[n * 16 + lm];
        acc[n] = (f32x4){bv, bv, bv, bv};
    }
#pragma unroll
    for (int ks = 0; ks < 4; ++ks) {
        uint4e av = __builtin_nontemporal_load(
            (const uint4e*)(zb + (size_t)(row0 + w * 16 + lm) * 64 + ks * 16 + lk * 4));
        short8 a = *(short8*)&av;
#pragma unroll
        for (int n = 0; n < 8; ++n) {
            uint4 bv4 = *(const uint4*)(w1b + (size_t)(n * 16 + lm) * 64 + ks * 16 + lk * 4);
            short8 b = *(short8*)&bv4;
            acc[n] = __builtin_amdgcn_mfma_f32_16x16x32_bf16(a, b, acc[n], 0, 0, 0);
        }
    }
#pragma unroll
    for (int n = 0; n < 8; ++n)
#pragma unroll
        for (int q = 0; q < 4; ++q)
            z1[w * 16 + lk * 4 + q][n * 16 + lm] = fmaxf(acc[n][q], 0.f);
    // (no barrier: phase 2 reads only this wave's rows)

    // ---- phase 2: h = z1 @ W2^T + b2 ----
#pragma unroll
    for (int n = 0; n < 8; ++n) {
        float bv = b2[n * 16 + lm];
        acc[n] = (f32x4){bv, bv, bv, bv};
    }
#pragma unroll
    for (int ks = 0; ks < 4; ++ks) {
        float4 f0 = *(const float4*)&z1[w * 16 + lm][ks * 32 + lk * 8];
        float4 f1 = *(const float4*)&z1[w * 16 + lm][ks * 32 + lk * 8 + 4];
        uint4 ua;
        ua.x = f2bf_pair(f0.x, f0.y);
        ua.y = f2bf_pair(f0.z, f0.w);
        ua.z = f2bf_pair(f1.x, f1.y);
        ua.w = f2bf_pair(f1.z, f1.w);
        short8 a = *(short8*)&ua;
#pragma unroll
        for (int n = 0; n < 8; ++n) {
            uint4 bv4 = *(const uint4*)(w2b + (size_t)(n * 16 + lm) * 64 + ks * 16 + lk * 4);
            short8 b = *(short8*)&bv4;
            acc[n] = __builtin_amdgcn_mfma_f32_16x16x32_bf16(a, b, acc[n], 0, 0, 0);
        }
    }
    // stage phase-2 result in LDS (own wave's rows)
#pragma unroll
    for (int n = 0; n < 8; ++n)
#pragma unroll
        for (int q = 0; q < 4; ++q)
            z1[w * 16 + lk * 4 + q][n * 16 + lm] = acc[n][q];

    if constexpr (!LAST) {
        __syncthreads();   // repack reads all waves' rows
        for (int i = t; i < 2048; i += 256) {
            int row = i >> 5, j = i & 31;
            float4 v = *(const float4*)&z1[row][j * 4];
            uint2 o;
            o.x = f2bf_pair(v.x, v.y);
            o.y = f2bf_pair(v.z, v.w);
            *(uint2*)&hout[(size_t)(row0 + row) * 64 + j * 2] = o;
        }
    } else {
        // ---- phase 3 (classifier): out = h @ Wc^T, Wc bf16 48x128 (rows 40+ zero) ----
        f32x4 acc3[3];
#pragma unroll
        for (int n = 0; n < 3; ++n) acc3[n] = (f32x4){0.f, 0.f, 0.f, 0.f};
#pragma unroll
        for (int ks = 0; ks < 4; ++ks) {
            float4 f0 = *(const float4*)&z1[w * 16 + lm][ks * 32 + lk * 8];
            float4 f1 = *(const float4*)&z1[w * 16 + lm][ks * 32 + lk * 8 + 4];
            uint4 ua;
            ua.x = f2bf_pair(f0.x, f0.y);
            ua.y = f2bf_pair(f0.z, f0.w);
            ua.z = f2bf_pair(f1.x, f1.y);
            ua.w = f2bf_pair(f1.z, f1.w);
            short8 a = *(short8*)&ua;
#pragma unroll
            for (int n = 0; n < 3; ++n) {
                uint4 bv4 = *(const uint4*)(wcb + (size_t)(n * 16 + lm) * 64 + ks * 16 + lk * 4);
                short8 b = *(short8*)&bv4;
                acc3[n] = __builtin_amdgcn_mfma_f32_16x16x32_bf16(a, b, acc3[n], 0, 0, 0);
            }
        }
#pragma unroll
        for (int n = 0; n < 3; ++n) {
            int cc = n * 16 + lm;
            if (cc < 40) {
#pragma unroll
                for (int q = 0; q < 4; ++q) {
                    int node = row0 + w * 16 + lk * 4 + q;
                    if (node < N_NODES) out[(size_t)node * 40 + cc] = acc3[n][q];
                }
            }
        }
    }
}

extern "C" void kernel_launch(void* const* d_in, const int* in_sizes, int n_in,
                              void* d_out, int out_size, void* d_ws, size_t ws_size,
                              hipStream_t stream) {
    const int* feats = (const int*)d_in[0];
    const int* src = (const int*)d_in[1];
    const int* dst = (const int*)d_in[2];
    const float* key_emb = (const float*)d_in[3];
    const float* val_emb = (const float*)d_in[4];
    const float* W1 = (const float*)d_in[5];
    const float* b1 = (const float*)d_in[6];
    const float* W2 = (const float*)d_in[7];
    const float* b2 = (const float*)d_in[8];
    const float* Wc = (const float*)d_in[9];
    float* out = (float*)d_out;

    char* ws = (char*)d_ws;
    auto carve = [&](size_t bytes) {
        char* p = ws;
        ws += (bytes + 255) & ~(size_t)255;
        return p;
    };
    uint* h0 = (uint*)carve((size_t)N_PAD * 64 * 4);
    uint* h1 = (uint*)carve((size_t)N_PAD * 64 * 4);
    uint* zb = (uint*)carve((size_t)N_PAD * 64 * 4);
    uint* w1b = (uint*)carve((size_t)3 * 128 * 64 * 4);
    uint* w2b = (uint*)carve((size_t)3 * 128 * 64 * 4);
    uint* wcb = (uint*)carve((size_t)48 * 64 * 4);
    int* row_start = (int*)carve((size_t)N_PAD * 4);
    int* counts = (int*)carve((size_t)N_PAD * 4);
    int* cursor16 = (int*)carve((size_t)NBUCK * 16 * 4);
    uint* col_tmp = (uint*)carve((size_t)NBUCK * BUCK_CAP * 4);   // 6.4 MB

    hipMemsetAsync(cursor16, 0, (size_t)NBUCK * 16 * 4, stream);

    edge_scatter_kernel<<<ESC_NCHUNK * 8, 256, 0, stream>>>(src, dst, cursor16, col_tmp);
    bucket_build_kernel<<<NBUCK, 256, 0, stream>>>(cursor16, col_tmp, row_start, counts);

    wconv_kernel<<<(3 * 128 * 64 + 255) / 256, 256, 0, stream>>>(W1, W2, Wc, w1b, w2b, wcb);
    embed_kernel<<<(N_NODES * 32 + 255) / 256, 256, 0, stream>>>(feats, key_emb, val_emb, h0);

    const int NBLK_MLP = (N_PAD + 63) / 64;      // 782
    const int NBLK_AGG = (N_NODES + 3) / 4;      // 12500

    agg_kernel<<<NBLK_AGG, 256, 0, stream>>>(h0, zb, row_start, counts, col_tmp);
    mlp_kernel<false><<<NBLK_MLP, 256, 0, stream>>>(zb, h1, w1b, b1, w2b, b2, nullptr, nullptr);
    agg_kernel<<<NBLK_AGG, 256, 0, stream>>>(h1, zb, row_start, counts, col_tmp);
    mlp_kernel<false><<<NBLK_MLP, 256, 0, stream>>>(zb, h0, w1b + 128 * 64, b1 + HID,
                                                    w2b + 128 * 64, b2 + HID, nullptr, nullptr);
    agg_kernel<<<NBLK_AGG, 256, 0, stream>>>(h0, zb, row_start, counts, col_tmp);
    mlp_kernel<true><<<NBLK_MLP, 256, 0, stream>>>(zb, nullptr, w1b + 2 * 128 * 64, b1 + 2 * HID,
                                                   w2b + 2 * 128 * 64, b2 + 2 * HID, wcb, out);
}

// Round 12
// 317.845 us; speedup vs baseline: 1.1324x; 1.1324x over previous
//
#include <hip/hip_runtime.h>

#define N_NODES 50000
#define N_PAD 50048      // rows padded to multiple of 64 so MLP needs no row guards
#define N_EDGES 800000
#define HID 128
#define NBUCK 98         // coarse buckets of 512 nodes (dst>>9)
#define BUCK_CAP 8704    // mean 8163, sigma ~90 -> +6 sigma
#define LBIN_CAP 48      // per-block per-bucket: mean 20.9, +6 sigma
#define ESC_CHUNK 2048
#define ESC_NCHUNK ((N_EDGES + ESC_CHUNK - 1) / ESC_CHUNK)   // 391

typedef unsigned int uint;
typedef __attribute__((ext_vector_type(8))) short short8;   // 8 bf16 = 4 VGPRs
typedef __attribute__((ext_vector_type(4))) float f32x4;

// ---- bf16 pack/unpack (RNE) ----
__device__ inline uint f2bf_pair(float x, float y) {
    uint ux = __float_as_uint(x);
    uint uy = __float_as_uint(y);
    ux = (ux + 0x7FFFu + ((ux >> 16) & 1u)) >> 16;
    uy = (uy + 0x7FFFu + ((uy >> 16) & 1u)) >> 16;
    return ux | (uy << 16);
}
__device__ inline float bf_lo(uint v) { return __uint_as_float(v << 16); }
__device__ inline float bf_hi(uint v) { return __uint_as_float(v & 0xFFFF0000u); }

// ---------------- CSR build, LDS-coalesced ----------------
// Phase 1: bin 2048 edges into 98 coarse buckets (dst>>9) in LDS, then write
// each bucket's run CONTIGUOUSLY after one bulk cursor reservation. Converts
// 800K random 4B global appends (28MB line-amplified writes) into ~21-edge
// dense runs (~5MB). Overflow (P~1e-5/run) takes a correct global slow path.
__global__ __launch_bounds__(256) void bin_scatter_kernel(const int* __restrict__ src,
                                                          const int* __restrict__ dst,
                                                          int* __restrict__ gcursor,
                                                          uint* __restrict__ col_tmp) {
    __shared__ uint lbin[NBUCK][LBIN_CAP];   // 18.4 KB
    __shared__ int lcnt[NBUCK], gbase[NBUCK];
    int t = threadIdx.x;
    int base = blockIdx.x * ESC_CHUNK;
    if (t < NBUCK) lcnt[t] = 0;
    __syncthreads();
#pragma unroll
    for (int i = 0; i < ESC_CHUNK / 256; ++i) {
        int e = base + i * 256 + t;
        if (e < N_EDGES) {
            int d = dst[e];
            int b = d >> 9;
            uint val = (uint)src[e] | ((uint)(d & 511) << 16);
            int p = atomicAdd(&lcnt[b], 1);
            if (p < LBIN_CAP) {
                lbin[b][p] = val;
            } else {                       // slow path: direct global append
                int gp = atomicAdd(&gcursor[b], 1);
                if (gp < BUCK_CAP) col_tmp[(size_t)b * BUCK_CAP + gp] = val;
            }
        }
    }
    __syncthreads();
    if (t < NBUCK) {
        int c = lcnt[t];
        if (c > LBIN_CAP) c = LBIN_CAP;
        gbase[t] = atomicAdd(&gcursor[t], c);
    }
    __syncthreads();
    for (int i = t; i < NBUCK * LBIN_CAP; i += 256) {
        int b = i / LBIN_CAP, slot = i % LBIN_CAP;
        int c = lcnt[b];
        if (c > LBIN_CAP) c = LBIN_CAP;
        if (slot < c) {
            int gp = gbase[b] + slot;
            if (gp < BUCK_CAP) col_tmp[(size_t)b * BUCK_CAP + gp] = lbin[b][slot];
        }
    }
}

// Phase 2: per bucket (512 nodes), sort edges by local node in LDS, write back
// dense, emit row_start/counts. In-place safe (full LDS copy before writes).
__global__ __launch_bounds__(512) void bucket_build_kernel(const int* __restrict__ gcursor,
                                                           uint* __restrict__ col_tmp,
                                                           int* __restrict__ row_start,
                                                           int* __restrict__ counts) {
    __shared__ uint edges[BUCK_CAP];              // 34.8 KB
    __shared__ int cnt[512], pre[512], cur[512], s[512];
    int b = blockIdx.x, t = threadIdx.x;
    int cntE = gcursor[b];
    if (cntE > BUCK_CAP) cntE = BUCK_CAP;
    uint* region = col_tmp + (size_t)b * BUCK_CAP;
    for (int i = t; i < cntE; i += 512) edges[i] = region[i];
    cnt[t] = 0;
    cur[t] = 0;
    __syncthreads();
    for (int i = t; i < cntE; i += 512) atomicAdd(&cnt[edges[i] >> 16], 1);
    __syncthreads();
    int v = cnt[t];
    s[t] = v;
    __syncthreads();
    for (int off = 1; off < 512; off <<= 1) {
        int add = (t >= off) ? s[t - off] : 0;
        __syncthreads();
        s[t] += add;
        __syncthreads();
    }
    pre[t] = s[t] - v;
    __syncthreads();
    for (int i = t; i < cntE; i += 512) {
        uint e = edges[i];
        int dl = e >> 16;
        int p = atomicAdd(&cur[dl], 1);
        region[pre[dl] + p] = e & 0xFFFFu;
    }
    int node = b * 512 + t;
    if (node < N_PAD) {
        row_start[node] = b * BUCK_CAP + pre[t];
        counts[node] = cnt[t];
    }
}

// ---------------- weights fp32 -> bf16 (once per launch) ----------------
__global__ void wconv_kernel(const float* __restrict__ W1, const float* __restrict__ W2,
                             const float* __restrict__ Wc,
                             uint* __restrict__ w1b, uint* __restrict__ w2b,
                             uint* __restrict__ wcb) {
    int i = blockIdx.x * 256 + threadIdx.x;   // bf16-pair index
    if (i < 3 * 128 * 64) {
        w1b[i] = f2bf_pair(W1[2 * i], W1[2 * i + 1]);
        w2b[i] = f2bf_pair(W2[2 * i], W2[2 * i + 1]);
    }
    if (i < 48 * 64) {   // Wc padded to 48 rows, rows 40-47 zero
        int r = i >> 6, q = i & 63;
        wcb[i] = (r < 40) ? f2bf_pair(Wc[r * 128 + 2 * q], Wc[r * 128 + 2 * q + 1]) : 0u;
    }
}

// ---------------- embedding -> bf16 h ----------------
__global__ void embed_kernel(const int* __restrict__ feats, const float* __restrict__ key_emb,
                             const float* __restrict__ val_emb, uint* __restrict__ h) {
    int idx = blockIdx.x * 256 + threadIdx.x;
    if (idx >= N_NODES * 32) return;
    int n = idx >> 5, q = idx & 31;
    int f0 = feats[2 * n], f1 = feats[2 * n + 1];
    float4 a = ((const float4*)key_emb)[f0 * 32 + q];
    float4 b = ((const float4*)val_emb)[f1 * 32 + q];
    float r0 = fmaxf(a.x + b.x, 0.f), r1 = fmaxf(a.y + b.y, 0.f);
    float r2 = fmaxf(a.z + b.z, 0.f), r3 = fmaxf(a.w + b.w, 0.f);
    uint2 o;
    o.x = f2bf_pair(r0, r1);
    o.y = f2bf_pair(r2, r3);
    *(uint2*)&h[(size_t)n * 64 + q * 2] = o;
}

// ---------------- GIN aggregation: z = h + sum_{u in N(n)} h[u] ----------------
// one wave per node; lane = uint2 (4 bf16 feats), 32 lanes/row; two wave halves
// gather two different neighbors per instruction; shfl_xor(32) combine.
__global__ __launch_bounds__(256) void agg_kernel(const uint* __restrict__ hb,
                                                  uint* __restrict__ zb,
                                                  const int* __restrict__ row_start,
                                                  const int* __restrict__ counts,
                                                  const uint* __restrict__ col) {
    int node = blockIdx.x * 4 + (threadIdx.x >> 6);
    int l = threadIdx.x & 63;
    int half = l >> 5, fl = l & 31;
    const uint2* hp2 = (const uint2*)hb;
    int s = __builtin_amdgcn_readfirstlane(row_start[node]);
    int c = __builtin_amdgcn_readfirstlane(counts[node]);
    float a0 = 0.f, a1 = 0.f, a2 = 0.f, a3 = 0.f;
    int j = 0;
    for (; j + 8 <= c; j += 8) {
        int u0 = (int)col[s + j + half];
        int u1 = (int)col[s + j + 2 + half];
        int u2 = (int)col[s + j + 4 + half];
        int u3 = (int)col[s + j + 6 + half];
        uint2 v0 = hp2[(size_t)u0 * 32 + fl];
        uint2 v1 = hp2[(size_t)u1 * 32 + fl];
        uint2 v2 = hp2[(size_t)u2 * 32 + fl];
        uint2 v3 = hp2[(size_t)u3 * 32 + fl];
        a0 += (bf_lo(v0.x) + bf_lo(v1.x)) + (bf_lo(v2.x) + bf_lo(v3.x));
        a1 += (bf_hi(v0.x) + bf_hi(v1.x)) + (bf_hi(v2.x) + bf_hi(v3.x));
        a2 += (bf_lo(v0.y) + bf_lo(v1.y)) + (bf_lo(v2.y) + bf_lo(v3.y));
        a3 += (bf_hi(v0.y) + bf_hi(v1.y)) + (bf_hi(v2.y) + bf_hi(v3.y));
    }
    for (; j + 2 <= c; j += 2) {
        int u = (int)col[s + j + half];
        uint2 v = hp2[(size_t)u * 32 + fl];
        a0 += bf_lo(v.x); a1 += bf_hi(v.x); a2 += bf_lo(v.y); a3 += bf_hi(v.y);
    }
    if (j < c && half == 0) {
        int u = (int)col[s + j];
        uint2 v = hp2[(size_t)u * 32 + fl];
        a0 += bf_lo(v.x); a1 += bf_hi(v.x); a2 += bf_lo(v.y); a3 += bf_hi(v.y);
    }
    a0 += __shfl_xor(a0, 32);
    a1 += __shfl_xor(a1, 32);
    a2 += __shfl_xor(a2, 32);
    a3 += __shfl_xor(a3, 32);
    if (half == 0) {
        uint2 hv = hp2[(size_t)node * 32 + fl];   // self term
        a0 += bf_lo(hv.x); a1 += bf_hi(hv.x); a2 += bf_lo(hv.y); a3 += bf_hi(hv.y);
        uint2 o;
        o.x = f2bf_pair(a0, a1);
        o.y = f2bf_pair(a2, a3);
        ((uint2*)zb)[(size_t)node * 32 + fl] = o;
    }
}

// ---------------- MFMA 2-layer MLP (+ fused classifier when LAST) ----------------
// 4 waves/block; wave w owns rows [blk*64 + w*16, +16), all 128 cols.
// mfma_f32_16x16x32_bf16: A lane l holds z[row][ks*32+(l>>4)*8 ..+8] with row=+(l&15);
// B identical addressing on row-major W (out = z@W^T); C/D col=l&15, row=(l>>4)*4+q.
template <bool LAST>
__global__ __launch_bounds__(256) void mlp_kernel(
    const uint* __restrict__ zb, uint* __restrict__ hout,
    const uint* __restrict__ w1b, const float* __restrict__ b1,
    const uint* __restrict__ w2b, const float* __restrict__ b2,
    const uint* __restrict__ wcb, float* __restrict__ out) {
    __shared__ float z1[64][132];   // stride 132 -> conflict-free, 33 KB
    int t = threadIdx.x;
    int w = t >> 6, l = t & 63;
    int lm = l & 15, lk = l >> 4;
    int row0 = blockIdx.x * 64;

    f32x4 acc[8];
    // ---- phase 1: z1 = relu(z @ W1^T + b1) ----
#pragma unroll
    for (int n = 0; n < 8; ++n) {
        float bv = b1[n * 16 + lm];
        acc[n] = (f32x4){bv, bv, bv, bv};
    }
#pragma unroll
    for (int ks = 0; ks < 4; ++ks) {
        uint4 av = *(const uint4*)(zb + (size_t)(row0 + w * 16 + lm) * 64 + ks * 16 + lk * 4);
        short8 a = *(short8*)&av;
#pragma unroll
        for (int n = 0; n < 8; ++n) {
            uint4 bv4 = *(const uint4*)(w1b + (size_t)(n * 16 + lm) * 64 + ks * 16 + lk * 4);
            short8 b = *(short8*)&bv4;
            acc[n] = __builtin_amdgcn_mfma_f32_16x16x32_bf16(a, b, acc[n], 0, 0, 0);
        }
    }
#pragma unroll
    for (int n = 0; n < 8; ++n)
#pragma unroll
        for (int q = 0; q < 4; ++q)
            z1[w * 16 + lk * 4 + q][n * 16 + lm] = fmaxf(acc[n][q], 0.f);
    // (no barrier: phase 2 reads only this wave's rows)

    // ---- phase 2: h = z1 @ W2^T + b2 ----
#pragma unroll
    for (int n = 0; n < 8; ++n) {
        float bv = b2[n * 16 + lm];
        acc[n] = (f32x4){bv, bv, bv, bv};
    }
#pragma unroll
    for (int ks = 0; ks < 4; ++ks) {
        float4 f0 = *(const float4*)&z1[w * 16 + lm][ks * 32 + lk * 8];
        float4 f1 = *(const float4*)&z1[w * 16 + lm][ks * 32 + lk * 8 + 4];
        uint4 ua;
        ua.x = f2bf_pair(f0.x, f0.y);
        ua.y = f2bf_pair(f0.z, f0.w);
        ua.z = f2bf_pair(f1.x, f1.y);
        ua.w = f2bf_pair(f1.z, f1.w);
        short8 a = *(short8*)&ua;
#pragma unroll
        for (int n = 0; n < 8; ++n) {
            uint4 bv4 = *(const uint4*)(w2b + (size_t)(n * 16 + lm) * 64 + ks * 16 + lk * 4);
            short8 b = *(short8*)&bv4;
            acc[n] = __builtin_amdgcn_mfma_f32_16x16x32_bf16(a, b, acc[n], 0, 0, 0);
        }
    }
    // stage phase-2 result in LDS (own wave's rows)
#pragma unroll
    for (int n = 0; n < 8; ++n)
#pragma unroll
        for (int q = 0; q < 4; ++q)
            z1[w * 16 + lk * 4 + q][n * 16 + lm] = acc[n][q];

    if constexpr (!LAST) {
        __syncthreads();   // repack reads all waves' rows
        for (int i = t; i < 2048; i += 256) {
            int row = i >> 5, j = i & 31;
            float4 v = *(const float4*)&z1[row][j * 4];
            uint2 o;
            o.x = f2bf_pair(v.x, v.y);
            o.y = f2bf_pair(v.z, v.w);
            *(uint2*)&hout[(size_t)(row0 + row) * 64 + j * 2] = o;
        }
    } else {
        // ---- phase 3 (classifier): out = h @ Wc^T, Wc bf16 48x128 (rows 40+ zero) ----
        f32x4 acc3[3];
#pragma unroll
        for (int n = 0; n < 3; ++n) acc3[n] = (f32x4){0.f, 0.f, 0.f, 0.f};
#pragma unroll
        for (int ks = 0; ks < 4; ++ks) {
            float4 f0 = *(const float4*)&z1[w * 16 + lm][ks * 32 + lk * 8];
            float4 f1 = *(const float4*)&z1[w * 16 + lm][ks * 32 + lk * 8 + 4];
            uint4 ua;
            ua.x = f2bf_pair(f0.x, f0.y);
            ua.y = f2bf_pair(f0.z, f0.w);
            ua.z = f2bf_pair(f1.x, f1.y);
            ua.w = f2bf_pair(f1.z, f1.w);
            short8 a = *(short8*)&ua;
#pragma unroll
            for (int n = 0; n < 3; ++n) {
                uint4 bv4 = *(const uint4*)(wcb + (size_t)(n * 16 + lm) * 64 + ks * 16 + lk * 4);
                short8 b = *(short8*)&bv4;
                acc3[n] = __builtin_amdgcn_mfma_f32_16x16x32_bf16(a, b, acc3[n], 0, 0, 0);
            }
        }
#pragma unroll
        for (int n = 0; n < 3; ++n) {
            int cc = n * 16 + lm;
            if (cc < 40) {
#pragma unroll
                for (int q = 0; q < 4; ++q) {
                    int node = row0 + w * 16 + lk * 4 + q;
                    if (node < N_NODES) out[(size_t)node * 40 + cc] = acc3[n][q];
                }
            }
        }
    }
}

extern "C" void kernel_launch(void* const* d_in, const int* in_sizes, int n_in,
                              void* d_out, int out_size, void* d_ws, size_t ws_size,
                              hipStream_t stream) {
    const int* feats = (const int*)d_in[0];
    const int* src = (const int*)d_in[1];
    const int* dst = (const int*)d_in[2];
    const float* key_emb = (const float*)d_in[3];
    const float* val_emb = (const float*)d_in[4];
    const float* W1 = (const float*)d_in[5];
    const float* b1 = (const float*)d_in[6];
    const float* W2 = (const float*)d_in[7];
    const float* b2 = (const float*)d_in[8];
    const float* Wc = (const float*)d_in[9];
    float* out = (float*)d_out;

    char* ws = (char*)d_ws;
    auto carve = [&](size_t bytes) {
        char* p = ws;
        ws += (bytes + 255) & ~(size_t)255;
        return p;
    };
    uint* h0 = (uint*)carve((size_t)N_PAD * 64 * 4);
    uint* h1 = (uint*)carve((size_t)N_PAD * 64 * 4);
    uint* zb = (uint*)carve((size_t)N_PAD * 64 * 4);
    uint* w1b = (uint*)carve((size_t)3 * 128 * 64 * 4);
    uint* w2b = (uint*)carve((size_t)3 * 128 * 64 * 4);
    uint* wcb = (uint*)carve((size_t)48 * 64 * 4);
    int* row_start = (int*)carve((size_t)N_PAD * 4);
    int* counts = (int*)carve((size_t)N_PAD * 4);
    int* gcursor = (int*)carve(512);
    uint* col_tmp = (uint*)carve((size_t)NBUCK * BUCK_CAP * 4);   // 3.4 MB

    hipMemsetAsync(gcursor, 0, 512, stream);

    bin_scatter_kernel<<<ESC_NCHUNK, 256, 0, stream>>>(src, dst, gcursor, col_tmp);
    bucket_build_kernel<<<NBUCK, 512, 0, stream>>>(gcursor, col_tmp, row_start, counts);

    wconv_kernel<<<(3 * 128 * 64 + 255) / 256, 256, 0, stream>>>(W1, W2, Wc, w1b, w2b, wcb);
    embed_kernel<<<(N_NODES * 32 + 255) / 256, 256, 0, stream>>>(feats, key_emb, val_emb, h0);

    const int NBLK_MLP = (N_PAD + 63) / 64;      // 782
    const int NBLK_AGG = (N_NODES + 3) / 4;      // 12500

    agg_kernel<<<NBLK_AGG, 256, 0, stream>>>(h0, zb, row_start, counts, col_tmp);
    mlp_kernel<false><<<NBLK_MLP, 256, 0, stream>>>(zb, h1, w1b, b1, w2b, b2, nullptr, nullptr);
    agg_kernel<<<NBLK_AGG, 256, 0, stream>>>(h1, zb, row_start, counts, col_tmp);
    mlp_kernel<false><<<NBLK_MLP, 256, 0, stream>>>(zb, h0, w1b + 128 * 64, b1 + HID,
                                                    w2b + 128 * 64, b2 + HID, nullptr, nullptr);
    agg_kernel<<<NBLK_AGG, 256, 0, stream>>>(h0, zb, row_start, counts, col_tmp);
    mlp_kernel<true><<<NBLK_MLP, 256, 0, stream>>>(zb, nullptr, w1b + 2 * 128 * 64, b1 + 2 * HID,
                                                   w2b + 2 * 128 * 64, b2 + 2 * HID, wcb, out);
}

// Round 13
// 306.416 us; speedup vs baseline: 1.1746x; 1.0373x over previous
//
#include <hip/hip_runtime.h>

#define N_NODES 50000
#define N_PAD 50048      // rows padded to multiple of 64 so MLP needs no row guards
#define N_EDGES 800000
#define HID 128
#define NBUCK 98         // coarse buckets of 512 nodes (dst>>9)
#define BUCK_CAP 8704    // mean 8163, sigma ~90 -> +6 sigma
#define LBIN_CAP 48      // per-block per-bucket: mean 20.9, +6 sigma
#define ESC_CHUNK 2048
#define ESC_NCHUNK ((N_EDGES + ESC_CHUNK - 1) / ESC_CHUNK)   // 391

typedef unsigned int uint;
typedef __attribute__((ext_vector_type(8))) short short8;   // 8 bf16 = 4 VGPRs
typedef __attribute__((ext_vector_type(4))) float f32x4;

// ---- bf16 pack/unpack (RNE) ----
__device__ inline uint f2bf_pair(float x, float y) {
    uint ux = __float_as_uint(x);
    uint uy = __float_as_uint(y);
    ux = (ux + 0x7FFFu + ((ux >> 16) & 1u)) >> 16;
    uy = (uy + 0x7FFFu + ((uy >> 16) & 1u)) >> 16;
    return ux | (uy << 16);
}
__device__ inline float bf_lo(uint v) { return __uint_as_float(v << 16); }
__device__ inline float bf_hi(uint v) { return __uint_as_float(v & 0xFFFF0000u); }

// ---------------- CSR build, LDS-coalesced ----------------
__global__ __launch_bounds__(256) void bin_scatter_kernel(const int* __restrict__ src,
                                                          const int* __restrict__ dst,
                                                          int* __restrict__ gcursor,
                                                          uint* __restrict__ col_tmp) {
    __shared__ uint lbin[NBUCK][LBIN_CAP];   // 18.4 KB
    __shared__ int lcnt[NBUCK], gbase[NBUCK];
    int t = threadIdx.x;
    int base = blockIdx.x * ESC_CHUNK;
    if (t < NBUCK) lcnt[t] = 0;
    __syncthreads();
#pragma unroll
    for (int i = 0; i < ESC_CHUNK / 256; ++i) {
        int e = base + i * 256 + t;
        if (e < N_EDGES) {
            int d = dst[e];
            int b = d >> 9;
            uint val = (uint)src[e] | ((uint)(d & 511) << 16);
            int p = atomicAdd(&lcnt[b], 1);
            if (p < LBIN_CAP) {
                lbin[b][p] = val;
            } else {                       // slow path: direct global append
                int gp = atomicAdd(&gcursor[b], 1);
                if (gp < BUCK_CAP) col_tmp[(size_t)b * BUCK_CAP + gp] = val;
            }
        }
    }
    __syncthreads();
    if (t < NBUCK) {
        int c = lcnt[t];
        if (c > LBIN_CAP) c = LBIN_CAP;
        gbase[t] = atomicAdd(&gcursor[t], c);
    }
    __syncthreads();
    for (int i = t; i < NBUCK * LBIN_CAP; i += 256) {
        int b = i / LBIN_CAP, slot = i % LBIN_CAP;
        int c = lcnt[b];
        if (c > LBIN_CAP) c = LBIN_CAP;
        if (slot < c) {
            int gp = gbase[b] + slot;
            if (gp < BUCK_CAP) col_tmp[(size_t)b * BUCK_CAP + gp] = lbin[b][slot];
        }
    }
}

__global__ __launch_bounds__(512) void bucket_build_kernel(const int* __restrict__ gcursor,
                                                           uint* __restrict__ col_tmp,
                                                           int* __restrict__ row_start,
                                                           int* __restrict__ counts) {
    __shared__ uint edges[BUCK_CAP];              // 34.8 KB
    __shared__ int cnt[512], pre[512], cur[512], s[512];
    int b = blockIdx.x, t = threadIdx.x;
    int cntE = gcursor[b];
    if (cntE > BUCK_CAP) cntE = BUCK_CAP;
    uint* region = col_tmp + (size_t)b * BUCK_CAP;
    for (int i = t; i < cntE; i += 512) edges[i] = region[i];
    cnt[t] = 0;
    cur[t] = 0;
    __syncthreads();
    for (int i = t; i < cntE; i += 512) atomicAdd(&cnt[edges[i] >> 16], 1);
    __syncthreads();
    int v = cnt[t];
    s[t] = v;
    __syncthreads();
    for (int off = 1; off < 512; off <<= 1) {
        int add = (t >= off) ? s[t - off] : 0;
        __syncthreads();
        s[t] += add;
        __syncthreads();
    }
    pre[t] = s[t] - v;
    __syncthreads();
    for (int i = t; i < cntE; i += 512) {
        uint e = edges[i];
        int dl = e >> 16;
        int p = atomicAdd(&cur[dl], 1);
        region[pre[dl] + p] = e & 0xFFFFu;
    }
    int node = b * 512 + t;
    if (node < N_PAD) {
        row_start[node] = b * BUCK_CAP + pre[t];
        counts[node] = cnt[t];
    }
}

// ---------------- embedding -> bf16 h, + weight fp32->bf16 convert (merged) ------
#define EMB_BLOCKS ((N_NODES * 32 + 255) / 256)   // 6250
__global__ void embed_wconv_kernel(const int* __restrict__ feats,
                                   const float* __restrict__ key_emb,
                                   const float* __restrict__ val_emb, uint* __restrict__ h,
                                   const float* __restrict__ W1, const float* __restrict__ W2,
                                   const float* __restrict__ Wc,
                                   uint* __restrict__ w1b, uint* __restrict__ w2b,
                                   uint* __restrict__ wcb) {
    if (blockIdx.x >= EMB_BLOCKS) {   // weight-convert tail blocks
        int i = (blockIdx.x - EMB_BLOCKS) * 256 + threadIdx.x;
        if (i < 3 * 128 * 64) {
            w1b[i] = f2bf_pair(W1[2 * i], W1[2 * i + 1]);
            w2b[i] = f2bf_pair(W2[2 * i], W2[2 * i + 1]);
        }
        if (i < 48 * 64) {   // Wc padded to 48 rows, rows 40-47 zero
            int r = i >> 6, q = i & 63;
            wcb[i] = (r < 40) ? f2bf_pair(Wc[r * 128 + 2 * q], Wc[r * 128 + 2 * q + 1]) : 0u;
        }
        return;
    }
    int idx = blockIdx.x * 256 + threadIdx.x;
    if (idx >= N_NODES * 32) return;
    int n = idx >> 5, q = idx & 31;
    int f0 = feats[2 * n], f1 = feats[2 * n + 1];
    float4 a = ((const float4*)key_emb)[f0 * 32 + q];
    float4 b = ((const float4*)val_emb)[f1 * 32 + q];
    float r0 = fmaxf(a.x + b.x, 0.f), r1 = fmaxf(a.y + b.y, 0.f);
    float r2 = fmaxf(a.z + b.z, 0.f), r3 = fmaxf(a.w + b.w, 0.f);
    uint2 o;
    o.x = f2bf_pair(r0, r1);
    o.y = f2bf_pair(r2, r3);
    *(uint2*)&h[(size_t)n * 64 + q * 2] = o;
}

// ---------------- GIN aggregation: z = h + sum_{u in N(n)} h[u] ----------------
// one wave per node; 4 groups x 16 lanes; lane = uint4 (8 bf16) so ONE dwordx4
// instruction fetches a FULL 256B neighbor row per group -> 4 rows per issue,
// up to 16 rows outstanding. Reduce across groups via shfl_xor(16/32).
__global__ __launch_bounds__(256) void agg_kernel(const uint* __restrict__ hb,
                                                  uint* __restrict__ zb,
                                                  const int* __restrict__ row_start,
                                                  const int* __restrict__ counts,
                                                  const uint* __restrict__ col) {
    int node = blockIdx.x * 4 + (threadIdx.x >> 6);
    int l = threadIdx.x & 63;
    int g = l >> 4, fl = l & 15;
    const uint4* hp4 = (const uint4*)hb;
    int s = __builtin_amdgcn_readfirstlane(row_start[node]);
    int c = __builtin_amdgcn_readfirstlane(counts[node]);
    float a0 = 0.f, a1 = 0.f, a2 = 0.f, a3 = 0.f, a4 = 0.f, a5 = 0.f, a6 = 0.f, a7 = 0.f;
    int j = 0;
#define ACC_ROW(u)                                                        \
    {                                                                     \
        uint4 v = hp4[(size_t)(u) * 16 + fl];                             \
        a0 += bf_lo(v.x); a1 += bf_hi(v.x); a2 += bf_lo(v.y);             \
        a3 += bf_hi(v.y); a4 += bf_lo(v.z); a5 += bf_hi(v.z);             \
        a6 += bf_lo(v.w); a7 += bf_hi(v.w);                               \
    }
    for (; j + 16 <= c; j += 16) {   // 16 rows in flight
        int u0 = (int)col[s + j + g];
        int u1 = (int)col[s + j + 4 + g];
        int u2 = (int)col[s + j + 8 + g];
        int u3 = (int)col[s + j + 12 + g];
        ACC_ROW(u0) ACC_ROW(u1) ACC_ROW(u2) ACC_ROW(u3)
    }
    if (j + 8 <= c) {
        int u0 = (int)col[s + j + g];
        int u1 = (int)col[s + j + 4 + g];
        ACC_ROW(u0) ACC_ROW(u1)
        j += 8;
    }
    if (j + 4 <= c) {
        int u = (int)col[s + j + g];
        ACC_ROW(u)
        j += 4;
    }
    if (g < c - j) {   // remainder 0..3 rows
        int u = (int)col[s + j + g];
        ACC_ROW(u)
    }
#undef ACC_ROW
    a0 += __shfl_xor(a0, 16); a1 += __shfl_xor(a1, 16);
    a2 += __shfl_xor(a2, 16); a3 += __shfl_xor(a3, 16);
    a4 += __shfl_xor(a4, 16); a5 += __shfl_xor(a5, 16);
    a6 += __shfl_xor(a6, 16); a7 += __shfl_xor(a7, 16);
    a0 += __shfl_xor(a0, 32); a1 += __shfl_xor(a1, 32);
    a2 += __shfl_xor(a2, 32); a3 += __shfl_xor(a3, 32);
    a4 += __shfl_xor(a4, 32); a5 += __shfl_xor(a5, 32);
    a6 += __shfl_xor(a6, 32); a7 += __shfl_xor(a7, 32);
    if (g == 0) {
        uint4 hv = hp4[(size_t)node * 16 + fl];   // self term
        a0 += bf_lo(hv.x); a1 += bf_hi(hv.x); a2 += bf_lo(hv.y); a3 += bf_hi(hv.y);
        a4 += bf_lo(hv.z); a5 += bf_hi(hv.z); a6 += bf_lo(hv.w); a7 += bf_hi(hv.w);
        uint4 o;
        o.x = f2bf_pair(a0, a1);
        o.y = f2bf_pair(a2, a3);
        o.z = f2bf_pair(a4, a5);
        o.w = f2bf_pair(a6, a7);
        ((uint4*)zb)[(size_t)node * 16 + fl] = o;
    }
}

// ---------------- MFMA 2-layer MLP (+ fused classifier when LAST) ----------------
// 4 waves/block; wave w owns rows [blk*64 + w*16, +16), all 128 cols.
// mfma_f32_16x16x32_bf16: A lane l holds z[row][ks*32+(l>>4)*8 ..+8] with row=+(l&15);
// B identical addressing on row-major W (out = z@W^T); C/D col=l&15, row=(l>>4)*4+q.
template <bool LAST>
__global__ __launch_bounds__(256) void mlp_kernel(
    const uint* __restrict__ zb, uint* __restrict__ hout,
    const uint* __restrict__ w1b, const float* __restrict__ b1,
    const uint* __restrict__ w2b, const float* __restrict__ b2,
    const uint* __restrict__ wcb, float* __restrict__ out) {
    __shared__ float z1[64][132];   // stride 132 -> conflict-free, 33 KB
    int t = threadIdx.x;
    int w = t >> 6, l = t & 63;
    int lm = l & 15, lk = l >> 4;
    int row0 = blockIdx.x * 64;

    f32x4 acc[8];
    // ---- phase 1: z1 = relu(z @ W1^T + b1) ----
#pragma unroll
    for (int n = 0; n < 8; ++n) {
        float bv = b1[n * 16 + lm];
        acc[n] = (f32x4){bv, bv, bv, bv};
    }
#pragma unroll
    for (int ks = 0; ks < 4; ++ks) {
        uint4 av = *(const uint4*)(zb + (size_t)(row0 + w * 16 + lm) * 64 + ks * 16 + lk * 4);
        short8 a = *(short8*)&av;
#pragma unroll
        for (int n = 0; n < 8; ++n) {
            uint4 bv4 = *(const uint4*)(w1b + (size_t)(n * 16 + lm) * 64 + ks * 16 + lk * 4);
            short8 b = *(short8*)&bv4;
            acc[n] = __builtin_amdgcn_mfma_f32_16x16x32_bf16(a, b, acc[n], 0, 0, 0);
        }
    }
#pragma unroll
    for (int n = 0; n < 8; ++n)
#pragma unroll
        for (int q = 0; q < 4; ++q)
            z1[w * 16 + lk * 4 + q][n * 16 + lm] = fmaxf(acc[n][q], 0.f);
    // (no barrier: phase 2 reads only this wave's rows)

    // ---- phase 2: h = z1 @ W2^T + b2 ----
#pragma unroll
    for (int n = 0; n < 8; ++n) {
        float bv = b2[n * 16 + lm];
        acc[n] = (f32x4){bv, bv, bv, bv};
    }
#pragma unroll
    for (int ks = 0; ks < 4; ++ks) {
        float4 f0 = *(const float4*)&z1[w * 16 + lm][ks * 32 + lk * 8];
        float4 f1 = *(const float4*)&z1[w * 16 + lm][ks * 32 + lk * 8 + 4];
        uint4 ua;
        ua.x = f2bf_pair(f0.x, f0.y);
        ua.y = f2bf_pair(f0.z, f0.w);
        ua.z = f2bf_pair(f1.x, f1.y);
        ua.w = f2bf_pair(f1.z, f1.w);
        short8 a = *(short8*)&ua;
#pragma unroll
        for (int n = 0; n < 8; ++n) {
            uint4 bv4 = *(const uint4*)(w2b + (size_t)(n * 16 + lm) * 64 + ks * 16 + lk * 4);
            short8 b = *(short8*)&bv4;
            acc[n] = __builtin_amdgcn_mfma_f32_16x16x32_bf16(a, b, acc[n], 0, 0, 0);
        }
    }
    // stage phase-2 result in LDS (own wave's rows)
#pragma unroll
    for (int n = 0; n < 8; ++n)
#pragma unroll
        for (int q = 0; q < 4; ++q)
            z1[w * 16 + lk * 4 + q][n * 16 + lm] = acc[n][q];

    if constexpr (!LAST) {
        __syncthreads();   // repack reads all waves' rows
        for (int i = t; i < 2048; i += 256) {
            int row = i >> 5, j = i & 31;
            float4 v = *(const float4*)&z1[row][j * 4];
            uint2 o;
            o.x = f2bf_pair(v.x, v.y);
            o.y = f2bf_pair(v.z, v.w);
            *(uint2*)&hout[(size_t)(row0 + row) * 64 + j * 2] = o;
        }
    } else {
        // ---- phase 3 (classifier): out = h @ Wc^T, Wc bf16 48x128 (rows 40+ zero) ----
        f32x4 acc3[3];
#pragma unroll
        for (int n = 0; n < 3; ++n) acc3[n] = (f32x4){0.f, 0.f, 0.f, 0.f};
#pragma unroll
        for (int ks = 0; ks < 4; ++ks) {
            float4 f0 = *(const float4*)&z1[w * 16 + lm][ks * 32 + lk * 8];
            float4 f1 = *(const float4*)&z1[w * 16 + lm][ks * 32 + lk * 8 + 4];
            uint4 ua;
            ua.x = f2bf_pair(f0.x, f0.y);
            ua.y = f2bf_pair(f0.z, f0.w);
            ua.z = f2bf_pair(f1.x, f1.y);
            ua.w = f2bf_pair(f1.z, f1.w);
            short8 a = *(short8*)&ua;
#pragma unroll
            for (int n = 0; n < 3; ++n) {
                uint4 bv4 = *(const uint4*)(wcb + (size_t)(n * 16 + lm) * 64 + ks * 16 + lk * 4);
                short8 b = *(short8*)&bv4;
                acc3[n] = __builtin_amdgcn_mfma_f32_16x16x32_bf16(a, b, acc3[n], 0, 0, 0);
            }
        }
#pragma unroll
        for (int n = 0; n < 3; ++n) {
            int cc = n * 16 + lm;
            if (cc < 40) {
#pragma unroll
                for (int q = 0; q < 4; ++q) {
                    int node = row0 + w * 16 + lk * 4 + q;
                    if (node < N_NODES) out[(size_t)node * 40 + cc] = acc3[n][q];
                }
            }
        }
    }
}

extern "C" void kernel_launch(void* const* d_in, const int* in_sizes, int n_in,
                              void* d_out, int out_size, void* d_ws, size_t ws_size,
                              hipStream_t stream) {
    const int* feats = (const int*)d_in[0];
    const int* src = (const int*)d_in[1];
    const int* dst = (const int*)d_in[2];
    const float* key_emb = (const float*)d_in[3];
    const float* val_emb = (const float*)d_in[4];
    const float* W1 = (const float*)d_in[5];
    const float* b1 = (const float*)d_in[6];
    const float* W2 = (const float*)d_in[7];
    const float* b2 = (const float*)d_in[8];
    const float* Wc = (const float*)d_in[9];
    float* out = (float*)d_out;

    char* ws = (char*)d_ws;
    auto carve = [&](size_t bytes) {
        char* p = ws;
        ws += (bytes + 255) & ~(size_t)255;
        return p;
    };
    uint* h0 = (uint*)carve((size_t)N_PAD * 64 * 4);
    uint* h1 = (uint*)carve((size_t)N_PAD * 64 * 4);
    uint* zb = (uint*)carve((size_t)N_PAD * 64 * 4);
    uint* w1b = (uint*)carve((size_t)3 * 128 * 64 * 4);
    uint* w2b = (uint*)carve((size_t)3 * 128 * 64 * 4);
    uint* wcb = (uint*)carve((size_t)48 * 64 * 4);
    int* row_start = (int*)carve((size_t)N_PAD * 4);
    int* counts = (int*)carve((size_t)N_PAD * 4);
    int* gcursor = (int*)carve(512);
    uint* col_tmp = (uint*)carve((size_t)NBUCK * BUCK_CAP * 4);   // 3.4 MB

    hipMemsetAsync(gcursor, 0, 512, stream);

    bin_scatter_kernel<<<ESC_NCHUNK, 256, 0, stream>>>(src, dst, gcursor, col_tmp);
    embed_wconv_kernel<<<EMB_BLOCKS + 96, 256, 0, stream>>>(feats, key_emb, val_emb, h0,
                                                            W1, W2, Wc, w1b, w2b, wcb);
    bucket_build_kernel<<<NBUCK, 512, 0, stream>>>(gcursor, col_tmp, row_start, counts);

    const int NBLK_MLP = (N_PAD + 63) / 64;      // 782
    const int NBLK_AGG = (N_NODES + 3) / 4;      // 12500

    agg_kernel<<<NBLK_AGG, 256, 0, stream>>>(h0, zb, row_start, counts, col_tmp);
    mlp_kernel<false><<<NBLK_MLP, 256, 0, stream>>>(zb, h1, w1b, b1, w2b, b2, nullptr, nullptr);
    agg_kernel<<<NBLK_AGG, 256, 0, stream>>>(h1, zb, row_start, counts, col_tmp);
    mlp_kernel<false><<<NBLK_MLP, 256, 0, stream>>>(zb, h0, w1b + 128 * 64, b1 + HID,
                                                    w2b + 128 * 64, b2 + HID, nullptr, nullptr);
    agg_kernel<<<NBLK_AGG, 256, 0, stream>>>(h0, zb, row_start, counts, col_tmp);
    mlp_kernel<true><<<NBLK_MLP, 256, 0, stream>>>(zb, nullptr, w1b + 2 * 128 * 64, b1 + 2 * HID,
                                                   w2b + 2 * 128 * 64, b2 + 2 * HID, wcb, out);
}

// Round 14
// 298.593 us; speedup vs baseline: 1.2054x; 1.0262x over previous
//
#include <hip/hip_runtime.h>

#define N_NODES 50000
#define N_PAD 50048      // rows padded: 1564 * 32 exactly
#define N_EDGES 800000
#define HID 128
#define NBUCK 98         // coarse buckets of 512 nodes (dst>>9)
#define BUCK_CAP 8704    // mean 8163, sigma ~90 -> +6 sigma
#define LBIN_CAP 48      // per-block per-bucket: mean 20.9, +6 sigma
#define ESC_CHUNK 2048
#define ESC_NCHUNK ((N_EDGES + ESC_CHUNK - 1) / ESC_CHUNK)   // 391

typedef unsigned int uint;
typedef __attribute__((ext_vector_type(8))) short short8;   // 8 bf16 = 4 VGPRs
typedef __attribute__((ext_vector_type(4))) float f32x4;

// ---- bf16 pack/unpack (RNE) ----
__device__ inline uint f2bf_pair(float x, float y) {
    uint ux = __float_as_uint(x);
    uint uy = __float_as_uint(y);
    ux = (ux + 0x7FFFu + ((ux >> 16) & 1u)) >> 16;
    uy = (uy + 0x7FFFu + ((uy >> 16) & 1u)) >> 16;
    return ux | (uy << 16);
}
__device__ inline float bf_lo(uint v) { return __uint_as_float(v << 16); }
__device__ inline float bf_hi(uint v) { return __uint_as_float(v & 0xFFFF0000u); }

// ---------------- CSR build, LDS-coalesced ----------------
__global__ __launch_bounds__(256) void bin_scatter_kernel(const int* __restrict__ src,
                                                          const int* __restrict__ dst,
                                                          int* __restrict__ gcursor,
                                                          uint* __restrict__ col_tmp) {
    __shared__ uint lbin[NBUCK][LBIN_CAP];   // 18.4 KB
    __shared__ int lcnt[NBUCK], gbase[NBUCK];
    int t = threadIdx.x;
    int base = blockIdx.x * ESC_CHUNK;
    if (t < NBUCK) lcnt[t] = 0;
    __syncthreads();
#pragma unroll
    for (int i = 0; i < ESC_CHUNK / 256; ++i) {
        int e = base + i * 256 + t;
        if (e < N_EDGES) {
            int d = dst[e];
            int b = d >> 9;
            uint val = (uint)src[e] | ((uint)(d & 511) << 16);
            int p = atomicAdd(&lcnt[b], 1);
            if (p < LBIN_CAP) {
                lbin[b][p] = val;
            } else {                       // slow path: direct global append
                int gp = atomicAdd(&gcursor[b], 1);
                if (gp < BUCK_CAP) col_tmp[(size_t)b * BUCK_CAP + gp] = val;
            }
        }
    }
    __syncthreads();
    if (t < NBUCK) {
        int c = lcnt[t];
        if (c > LBIN_CAP) c = LBIN_CAP;
        gbase[t] = atomicAdd(&gcursor[t], c);
    }
    __syncthreads();
    for (int i = t; i < NBUCK * LBIN_CAP; i += 256) {
        int b = i / LBIN_CAP, slot = i % LBIN_CAP;
        int c = lcnt[b];
        if (c > LBIN_CAP) c = LBIN_CAP;
        if (slot < c) {
            int gp = gbase[b] + slot;
            if (gp < BUCK_CAP) col_tmp[(size_t)b * BUCK_CAP + gp] = lbin[b][slot];
        }
    }
}

__global__ __launch_bounds__(512) void bucket_build_kernel(const int* __restrict__ gcursor,
                                                           uint* __restrict__ col_tmp,
                                                           int* __restrict__ row_start,
                                                           int* __restrict__ counts) {
    __shared__ uint edges[BUCK_CAP];              // 34.8 KB
    __shared__ int cnt[512], pre[512], cur[512], s[512];
    int b = blockIdx.x, t = threadIdx.x;
    int cntE = gcursor[b];
    if (cntE > BUCK_CAP) cntE = BUCK_CAP;
    uint* region = col_tmp + (size_t)b * BUCK_CAP;
    for (int i = t; i < cntE; i += 512) edges[i] = region[i];
    cnt[t] = 0;
    cur[t] = 0;
    __syncthreads();
    for (int i = t; i < cntE; i += 512) atomicAdd(&cnt[edges[i] >> 16], 1);
    __syncthreads();
    int v = cnt[t];
    s[t] = v;
    __syncthreads();
    for (int off = 1; off < 512; off <<= 1) {
        int add = (t >= off) ? s[t - off] : 0;
        __syncthreads();
        s[t] += add;
        __syncthreads();
    }
    pre[t] = s[t] - v;
    __syncthreads();
    for (int i = t; i < cntE; i += 512) {
        uint e = edges[i];
        int dl = e >> 16;
        int p = atomicAdd(&cur[dl], 1);
        region[pre[dl] + p] = e & 0xFFFFu;
    }
    int node = b * 512 + t;
    if (node < N_PAD) {
        row_start[node] = b * BUCK_CAP + pre[t];
        counts[node] = cnt[t];
    }
}

// ---------------- embedding -> bf16 h, + weight fp32->bf16 convert (merged) ------
#define EMB_BLOCKS ((N_NODES * 32 + 255) / 256)   // 6250
__global__ void embed_wconv_kernel(const int* __restrict__ feats,
                                   const float* __restrict__ key_emb,
                                   const float* __restrict__ val_emb, uint* __restrict__ h,
                                   const float* __restrict__ W1, const float* __restrict__ W2,
                                   const float* __restrict__ Wc,
                                   uint* __restrict__ w1b, uint* __restrict__ w2b,
                                   uint* __restrict__ wcb) {
    if (blockIdx.x >= EMB_BLOCKS) {   // weight-convert tail blocks
        int i = (blockIdx.x - EMB_BLOCKS) * 256 + threadIdx.x;
        if (i < 3 * 128 * 64) {
            w1b[i] = f2bf_pair(W1[2 * i], W1[2 * i + 1]);
            w2b[i] = f2bf_pair(W2[2 * i], W2[2 * i + 1]);
        }
        if (i < 48 * 64) {   // Wc padded to 48 rows, rows 40-47 zero
            int r = i >> 6, q = i & 63;
            wcb[i] = (r < 40) ? f2bf_pair(Wc[r * 128 + 2 * q], Wc[r * 128 + 2 * q + 1]) : 0u;
        }
        return;
    }
    int idx = blockIdx.x * 256 + threadIdx.x;
    if (idx >= N_NODES * 32) return;
    int n = idx >> 5, q = idx & 31;
    int f0 = feats[2 * n], f1 = feats[2 * n + 1];
    float4 a = ((const float4*)key_emb)[f0 * 32 + q];
    float4 b = ((const float4*)val_emb)[f1 * 32 + q];
    float r0 = fmaxf(a.x + b.x, 0.f), r1 = fmaxf(a.y + b.y, 0.f);
    float r2 = fmaxf(a.z + b.z, 0.f), r3 = fmaxf(a.w + b.w, 0.f);
    uint2 o;
    o.x = f2bf_pair(r0, r1);
    o.y = f2bf_pair(r2, r3);
    *(uint2*)&h[(size_t)n * 64 + q * 2] = o;
}

// ---------------- GIN aggregation: z = h + sum_{u in N(n)} h[u] ----------------
// one wave per node; 4 groups x 16 lanes; lane = uint4 (8 bf16): one dwordx4 =
// a full 256B neighbor row per group -> 4 rows/issue, 16 outstanding.
__global__ __launch_bounds__(256) void agg_kernel(const uint* __restrict__ hb,
                                                  uint* __restrict__ zb,
                                                  const int* __restrict__ row_start,
                                                  const int* __restrict__ counts,
                                                  const uint* __restrict__ col) {
    int node = blockIdx.x * 4 + (threadIdx.x >> 6);
    int l = threadIdx.x & 63;
    int g = l >> 4, fl = l & 15;
    const uint4* hp4 = (const uint4*)hb;
    int s = __builtin_amdgcn_readfirstlane(row_start[node]);
    int c = __builtin_amdgcn_readfirstlane(counts[node]);
    float a0 = 0.f, a1 = 0.f, a2 = 0.f, a3 = 0.f, a4 = 0.f, a5 = 0.f, a6 = 0.f, a7 = 0.f;
    int j = 0;
#define ACC_ROW(u)                                                        \
    {                                                                     \
        uint4 v = hp4[(size_t)(u) * 16 + fl];                             \
        a0 += bf_lo(v.x); a1 += bf_hi(v.x); a2 += bf_lo(v.y);             \
        a3 += bf_hi(v.y); a4 += bf_lo(v.z); a5 += bf_hi(v.z);             \
        a6 += bf_lo(v.w); a7 += bf_hi(v.w);                               \
    }
    for (; j + 16 <= c; j += 16) {   // 16 rows in flight
        int u0 = (int)col[s + j + g];
        int u1 = (int)col[s + j + 4 + g];
        int u2 = (int)col[s + j + 8 + g];
        int u3 = (int)col[s + j + 12 + g];
        ACC_ROW(u0) ACC_ROW(u1) ACC_ROW(u2) ACC_ROW(u3)
    }
    if (j + 8 <= c) {
        int u0 = (int)col[s + j + g];
        int u1 = (int)col[s + j + 4 + g];
        ACC_ROW(u0) ACC_ROW(u1)
        j += 8;
    }
    if (j + 4 <= c) {
        int u = (int)col[s + j + g];
        ACC_ROW(u)
        j += 4;
    }
    if (g < c - j) {   // remainder 0..3 rows
        int u = (int)col[s + j + g];
        ACC_ROW(u)
    }
#undef ACC_ROW
    a0 += __shfl_xor(a0, 16); a1 += __shfl_xor(a1, 16);
    a2 += __shfl_xor(a2, 16); a3 += __shfl_xor(a3, 16);
    a4 += __shfl_xor(a4, 16); a5 += __shfl_xor(a5, 16);
    a6 += __shfl_xor(a6, 16); a7 += __shfl_xor(a7, 16);
    a0 += __shfl_xor(a0, 32); a1 += __shfl_xor(a1, 32);
    a2 += __shfl_xor(a2, 32); a3 += __shfl_xor(a3, 32);
    a4 += __shfl_xor(a4, 32); a5 += __shfl_xor(a5, 32);
    a6 += __shfl_xor(a6, 32); a7 += __shfl_xor(a7, 32);
    if (g == 0) {
        uint4 hv = hp4[(size_t)node * 16 + fl];   // self term
        a0 += bf_lo(hv.x); a1 += bf_hi(hv.x); a2 += bf_lo(hv.y); a3 += bf_hi(hv.y);
        a4 += bf_lo(hv.z); a5 += bf_hi(hv.z); a6 += bf_lo(hv.w); a7 += bf_hi(hv.w);
        uint4 o;
        o.x = f2bf_pair(a0, a1);
        o.y = f2bf_pair(a2, a3);
        o.z = f2bf_pair(a4, a5);
        o.w = f2bf_pair(a6, a7);
        ((uint4*)zb)[(size_t)node * 16 + fl] = o;
    }
}

// ---------------- MFMA 2-layer MLP, 32-row tile, column-split waves ----------------
// 4 waves/block; wave w: rows rw=(w>>1)*16, cols n0=(w&1)*4 (4x 16-col groups).
// Halved per-wave W footprint + 2x grid (1564 blocks, ~24 waves/CU) vs 64-row tile.
// mfma C/D: col=lane&15, row=(lane>>4)*4+q. Same issue order -> bitwise-identical.
template <bool LAST>
__global__ __launch_bounds__(256) void mlp_kernel(
    const uint* __restrict__ zb, uint* __restrict__ hout,
    const uint* __restrict__ w1b, const float* __restrict__ b1,
    const uint* __restrict__ w2b, const float* __restrict__ b2,
    const uint* __restrict__ wcb, float* __restrict__ out) {
    __shared__ float z1[32][132];   // 16.9 KB
    int t = threadIdx.x;
    int w = t >> 6, l = t & 63;
    int lm = l & 15, lk = l >> 4;
    int rw = (w >> 1) * 16;     // wave's row offset in tile
    int n0 = (w & 1) * 4;       // wave's first 16-col group
    int row0 = blockIdx.x * 32;

    f32x4 acc[4];
    // ---- phase 1: z1 = relu(z @ W1^T + b1), this wave: 16 rows x 64 cols ----
#pragma unroll
    for (int n = 0; n < 4; ++n) {
        float bv = b1[(n0 + n) * 16 + lm];
        acc[n] = (f32x4){bv, bv, bv, bv};
    }
#pragma unroll
    for (int ks = 0; ks < 4; ++ks) {
        uint4 av = *(const uint4*)(zb + (size_t)(row0 + rw + lm) * 64 + ks * 16 + lk * 4);
        short8 a = *(short8*)&av;
#pragma unroll
        for (int n = 0; n < 4; ++n) {
            uint4 bv4 = *(const uint4*)(w1b + (size_t)((n0 + n) * 16 + lm) * 64 + ks * 16 + lk * 4);
            short8 b = *(short8*)&bv4;
            acc[n] = __builtin_amdgcn_mfma_f32_16x16x32_bf16(a, b, acc[n], 0, 0, 0);
        }
    }
#pragma unroll
    for (int n = 0; n < 4; ++n)
#pragma unroll
        for (int q = 0; q < 4; ++q)
            z1[rw + lk * 4 + q][(n0 + n) * 16 + lm] = fmaxf(acc[n][q], 0.f);
    __syncthreads();

    // ---- phase 2: h = z1 @ W2^T + b2 (A reads full 128-col rows from LDS) ----
#pragma unroll
    for (int n = 0; n < 4; ++n) {
        float bv = b2[(n0 + n) * 16 + lm];
        acc[n] = (f32x4){bv, bv, bv, bv};
    }
#pragma unroll
    for (int ks = 0; ks < 4; ++ks) {
        float4 f0 = *(const float4*)&z1[rw + lm][ks * 32 + lk * 8];
        float4 f1 = *(const float4*)&z1[rw + lm][ks * 32 + lk * 8 + 4];
        uint4 ua;
        ua.x = f2bf_pair(f0.x, f0.y);
        ua.y = f2bf_pair(f0.z, f0.w);
        ua.z = f2bf_pair(f1.x, f1.y);
        ua.w = f2bf_pair(f1.z, f1.w);
        short8 a = *(short8*)&ua;
#pragma unroll
        for (int n = 0; n < 4; ++n) {
            uint4 bv4 = *(const uint4*)(w2b + (size_t)((n0 + n) * 16 + lm) * 64 + ks * 16 + lk * 4);
            short8 b = *(short8*)&bv4;
            acc[n] = __builtin_amdgcn_mfma_f32_16x16x32_bf16(a, b, acc[n], 0, 0, 0);
        }
    }
    __syncthreads();   // rows now shared by 2 waves: all phase-2 reads must drain
#pragma unroll
    for (int n = 0; n < 4; ++n)
#pragma unroll
        for (int q = 0; q < 4; ++q)
            z1[rw + lk * 4 + q][(n0 + n) * 16 + lm] = acc[n][q];
    __syncthreads();

    if constexpr (!LAST) {
        // repack to bf16, coalesced uint2 stores (32 rows x 32 uint2)
        for (int i = t; i < 1024; i += 256) {
            int row = i >> 5, j = i & 31;
            float4 v = *(const float4*)&z1[row][j * 4];
            uint2 o;
            o.x = f2bf_pair(v.x, v.y);
            o.y = f2bf_pair(v.z, v.w);
            *(uint2*)&hout[(size_t)(row0 + row) * 64 + j * 2] = o;
        }
    } else {
        // ---- phase 3 (classifier): out = h @ Wc^T on waves 0,1 (16 rows each) ----
        if (w < 2) {
            int rr = w * 16;
            f32x4 acc3[3];
#pragma unroll
            for (int n = 0; n < 3; ++n) acc3[n] = (f32x4){0.f, 0.f, 0.f, 0.f};
#pragma unroll
            for (int ks = 0; ks < 4; ++ks) {
                float4 f0 = *(const float4*)&z1[rr + lm][ks * 32 + lk * 8];
                float4 f1 = *(const float4*)&z1[rr + lm][ks * 32 + lk * 8 + 4];
                uint4 ua;
                ua.x = f2bf_pair(f0.x, f0.y);
                ua.y = f2bf_pair(f0.z, f0.w);
                ua.z = f2bf_pair(f1.x, f1.y);
                ua.w = f2bf_pair(f1.z, f1.w);
                short8 a = *(short8*)&ua;
#pragma unroll
                for (int n = 0; n < 3; ++n) {
                    uint4 bv4 = *(const uint4*)(wcb + (size_t)(n * 16 + lm) * 64 + ks * 16 + lk * 4);
                    short8 b = *(short8*)&bv4;
                    acc3[n] = __builtin_amdgcn_mfma_f32_16x16x32_bf16(a, b, acc3[n], 0, 0, 0);
                }
            }
#pragma unroll
            for (int n = 0; n < 3; ++n) {
                int cc = n * 16 + lm;
                if (cc < 40) {
#pragma unroll
                    for (int q = 0; q < 4; ++q) {
                        int node = row0 + rr + lk * 4 + q;
                        if (node < N_NODES) out[(size_t)node * 40 + cc] = acc3[n][q];
                    }
                }
            }
        }
    }
}

extern "C" void kernel_launch(void* const* d_in, const int* in_sizes, int n_in,
                              void* d_out, int out_size, void* d_ws, size_t ws_size,
                              hipStream_t stream) {
    const int* feats = (const int*)d_in[0];
    const int* src = (const int*)d_in[1];
    const int* dst = (const int*)d_in[2];
    const float* key_emb = (const float*)d_in[3];
    const float* val_emb = (const float*)d_in[4];
    const float* W1 = (const float*)d_in[5];
    const float* b1 = (const float*)d_in[6];
    const float* W2 = (const float*)d_in[7];
    const float* b2 = (const float*)d_in[8];
    const float* Wc = (const float*)d_in[9];
    float* out = (float*)d_out;

    char* ws = (char*)d_ws;
    auto carve = [&](size_t bytes) {
        char* p = ws;
        ws += (bytes + 255) & ~(size_t)255;
        return p;
    };
    uint* h0 = (uint*)carve((size_t)N_PAD * 64 * 4);
    uint* h1 = (uint*)carve((size_t)N_PAD * 64 * 4);
    uint* zb = (uint*)carve((size_t)N_PAD * 64 * 4);
    uint* w1b = (uint*)carve((size_t)3 * 128 * 64 * 4);
    uint* w2b = (uint*)carve((size_t)3 * 128 * 64 * 4);
    uint* wcb = (uint*)carve((size_t)48 * 64 * 4);
    int* row_start = (int*)carve((size_t)N_PAD * 4);
    int* counts = (int*)carve((size_t)N_PAD * 4);
    int* gcursor = (int*)carve(512);
    uint* col_tmp = (uint*)carve((size_t)NBUCK * BUCK_CAP * 4);   // 3.4 MB

    hipMemsetAsync(gcursor, 0, 512, stream);

    bin_scatter_kernel<<<ESC_NCHUNK, 256, 0, stream>>>(src, dst, gcursor, col_tmp);
    embed_wconv_kernel<<<EMB_BLOCKS + 96, 256, 0, stream>>>(feats, key_emb, val_emb, h0,
                                                            W1, W2, Wc, w1b, w2b, wcb);
    bucket_build_kernel<<<NBUCK, 512, 0, stream>>>(gcursor, col_tmp, row_start, counts);

    const int NBLK_MLP = N_PAD / 32;             // 1564
    const int NBLK_AGG = (N_NODES + 3) / 4;      // 12500

    agg_kernel<<<NBLK_AGG, 256, 0, stream>>>(h0, zb, row_start, counts, col_tmp);
    mlp_kernel<false><<<NBLK_MLP, 256, 0, stream>>>(zb, h1, w1b, b1, w2b, b2, nullptr, nullptr);
    agg_kernel<<<NBLK_AGG, 256, 0, stream>>>(h1, zb, row_start, counts, col_tmp);
    mlp_kernel<false><<<NBLK_MLP, 256, 0, stream>>>(zb, h0, w1b + 128 * 64, b1 + HID,
                                                    w2b + 128 * 64, b2 + HID, nullptr, nullptr);
    agg_kernel<<<NBLK_AGG, 256, 0, stream>>>(h0, zb, row_start, counts, col_tmp);
    mlp_kernel<true><<<NBLK_MLP, 256, 0, stream>>>(zb, nullptr, w1b + 2 * 128 * 64, b1 + 2 * HID,
                                                   w2b + 2 * 128 * 64, b2 + 2 * HID, wcb, out);
}